// Round 2
// baseline (13387.964 us; speedup 1.0000x reference)
//
#include <hip/hip_runtime.h>
#include <hip/hip_bf16.h>

typedef short bf16x8 __attribute__((ext_vector_type(8)));
typedef float f32x4 __attribute__((ext_vector_type(4)));
typedef __hip_bfloat16 bf16;

#define NEGV -10000.0f

// Problem dims: B=64, T=256, E=300, H=500, K=64(tags), V=32000
// Padded: Ep=320, Hp=512, layer-1 input 2*Hp=1024, gate width 4096 = 2dir*4gate*512

__device__ __forceinline__ float sigm(float v) { return 1.0f / (1.0f + __expf(-v)); }
__device__ __forceinline__ float tanh_(float v) { float e = __expf(2.0f * v); return 1.0f - 2.0f / (e + 1.0f); }

// ---------------- weight packing into MFMA fragment-linear layout ----------------
// B-frag layout: dst[((nt*Kt + kt)*64 + lane)*8 + u] = B[kt*32 + (lane>>4)*8 + u][nt*16 + (lane&15)]

__global__ __launch_bounds__(256) void pack_w0(const float* __restrict__ wf, const float* __restrict__ wb,
                                               bf16* __restrict__ dst) {
  int idx = blockIdx.x * 256 + threadIdx.x;            // 4096*320 = 1310720
  int u = idx & 7, lane = (idx >> 3) & 63, rem = idx >> 9;
  int kt = rem % 10, nt = rem / 10;
  int n = (nt << 4) + (lane & 15), k = (kt << 5) + ((lane >> 4) << 3) + u;
  int d = n >> 11, g = (n >> 9) & 3, j = n & 511;
  float v = 0.f;
  if (j < 500 && k < 300) v = (d ? wb : wf)[(g * 500 + j) * 300 + k];
  dst[idx] = __float2bfloat16(v);
}

__global__ __launch_bounds__(256) void pack_whh(const float* __restrict__ w, bf16* __restrict__ dst) {
  int idx = blockIdx.x * 256 + threadIdx.x;            // 2048*512 = 1048576
  int u = idx & 7, lane = (idx >> 3) & 63, rem = idx >> 9;
  int kt = rem & 15, nt = rem >> 4;
  int n = (nt << 4) + (lane & 15), k = (kt << 5) + ((lane >> 4) << 3) + u;
  int g = n >> 9, j = n & 511;
  float v = 0.f;
  if (j < 500 && k < 500) v = w[(g * 500 + j) * 500 + k];
  dst[idx] = __float2bfloat16(v);
}

__global__ __launch_bounds__(256) void pack_w1(const float* __restrict__ wf, const float* __restrict__ wb,
                                               bf16* __restrict__ dst) {
  int idx = blockIdx.x * 256 + threadIdx.x;            // 4096*1024 = 4194304
  int u = idx & 7, lane = (idx >> 3) & 63, rem = idx >> 9;
  int kt = rem & 31, nt = rem >> 5;
  int n = (nt << 4) + (lane & 15), k = (kt << 5) + ((lane >> 4) << 3) + u;
  int d = n >> 11, g = (n >> 9) & 3, j = n & 511;
  int kk = k & 511;
  int ks = (k < 512) ? kk : 500 + kk;
  float v = 0.f;
  if (j < 500 && kk < 500) v = (d ? wb : wf)[(g * 500 + j) * 1000 + ks];
  dst[idx] = __float2bfloat16(v);
}

__global__ __launch_bounds__(256) void pack_wout(const float* __restrict__ w, bf16* __restrict__ dst) {
  int idx = blockIdx.x * 256 + threadIdx.x;            // 4*32*512 = 65536
  int u = idx & 7, lane = (idx >> 3) & 63, rem = idx >> 9;
  int kt = rem & 31, nt = rem >> 5;
  int n = (nt << 4) + (lane & 15), k = (kt << 5) + ((lane >> 4) << 3) + u;
  int kk = k & 511;
  int ks = (k < 512) ? kk : 500 + kk;
  float v = 0.f;
  if (kk < 500) v = w[n * 1000 + ks];
  dst[idx] = __float2bfloat16(v);
}

__global__ __launch_bounds__(256) void pack_bias(const float* __restrict__ bf_, const float* __restrict__ bb_,
                                                 float* __restrict__ dst) {
  int idx = blockIdx.x * 256 + threadIdx.x;            // 4096
  int d = idx >> 11, g = (idx >> 9) & 3, j = idx & 511;
  dst[idx] = (j < 500) ? (d ? bb_ : bf_)[g * 500 + j] : 0.f;
}

// ---------------- embedding gather -> bf16 [T*B][320] ----------------
__global__ __launch_bounds__(256) void embed_k(const int* __restrict__ x, const float* __restrict__ em,
                                               bf16* __restrict__ xs) {
  int idx = blockIdx.x * 256 + threadIdx.x;            // 16384*320
  int e = idx % 320;
  int row = idx / 320;
  int t = row >> 6, b = row & 63;
  float v = 0.f;
  if (e < 300) {
    int xv = x[b * 256 + t];
    v = em[(size_t)xv * 300 + e];
  }
  xs[idx] = __float2bfloat16(v);
}

// ---------------- generic MFMA GEMM: C[16384][4096] = A[16384][Kdim] @ Bfrag ----------------
__global__ __launch_bounds__(256) void gemm_nt(const bf16* __restrict__ A, const bf16* __restrict__ Bf,
                                               bf16* __restrict__ C, int Kdim, int Kt) {
  const int lane = threadIdx.x & 63, wave = threadIdx.x >> 6;
  const int lr = lane & 15, lh = lane >> 4;
  const int mb = blockIdx.x * 64;
  const int ntb = blockIdx.y * 16 + wave * 4;
  f32x4 acc[4][4] = {};
  for (int kt = 0; kt < Kt; ++kt) {
    bf16x8 a[4], b[4];
#pragma unroll
    for (int mt = 0; mt < 4; ++mt)
      a[mt] = *(const bf16x8*)(A + (size_t)(mb + mt * 16 + lr) * Kdim + kt * 32 + lh * 8);
#pragma unroll
    for (int q = 0; q < 4; ++q)
      b[q] = *(const bf16x8*)(Bf + ((size_t)(ntb + q) * Kt + kt) * 512 + lane * 8);
#pragma unroll
    for (int mt = 0; mt < 4; ++mt)
#pragma unroll
      for (int q = 0; q < 4; ++q)
        acc[mt][q] = __builtin_amdgcn_mfma_f32_16x16x32_bf16(a[mt], b[q], acc[mt][q], 0, 0, 0);
  }
#pragma unroll
  for (int mt = 0; mt < 4; ++mt)
#pragma unroll
    for (int q = 0; q < 4; ++q)
#pragma unroll
      for (int r = 0; r < 4; ++r) {
        int row = mb + mt * 16 + lh * 4 + r;
        int col = (ntb + q) * 16 + lr;
        C[(size_t)row * 4096 + col] = __float2bfloat16(acc[mt][q][r]);
      }
}

// ---------------- cooperative bidirectional LSTM layer ----------------
// grid(32 jb-tiles, 2 dirs), 256 threads (wave = gate). Custom per-direction barrier
// (32 arrivals/step) replaces grid.sync. Whh fragments preloaded to registers; pre[t]
// prefetched one step ahead so its HBM latency hides under the barrier spin.
__global__ __launch_bounds__(256) void lstm_layer(const bf16* __restrict__ pre, const bf16* __restrict__ whh,
                                                  const float* __restrict__ bias, bf16* __restrict__ hout,
                                                  unsigned int* __restrict__ barcnt) {
  const int tid = threadIdx.x, lane = tid & 63, wave = tid >> 6;
  const int lr = lane & 15, lh = lane >> 4;
  const int jb = blockIdx.x, dir = blockIdx.y;
  unsigned int* cnt = barcnt + dir;
  __shared__ float xch[4 * 64 * 17];  // [gate][batch][16 cols], stride-17 pad
  __shared__ float cst[64 * 16];      // c-state fp32, persistent across steps
  for (int i = tid; i < 1024; i += 256) cst[i] = 0.f;
  const int colg = dir * 2048 + wave * 512 + jb * 16 + lr;
  const float bb = bias[colg];
  const bf16* wbase = whh + ((size_t)(dir * 128 + wave * 32 + jb) * 16) * 512 + lane * 8;

  // preload recurrent weights into registers (16 frags = 64 VGPRs)
  bf16x8 wfrag[16];
#pragma unroll
  for (int kt = 0; kt < 16; ++kt) wfrag[kt] = *(const bf16x8*)(wbase + kt * 512);

  // prefetch pre for first step
  unsigned short pf[16];
  {
    const bf16* pr = pre + (size_t)(dir ? 255 : 0) * 64 * 4096 + colg;
#pragma unroll
    for (int mt = 0; mt < 4; ++mt)
#pragma unroll
      for (int r = 0; r < 4; ++r)
        pf[mt * 4 + r] = *(const unsigned short*)(pr + (size_t)(mt * 16 + lh * 4 + r) * 4096);
  }

  for (int s = 0; s < 256; ++s) {
    const int t = dir ? 255 - s : s;
    f32x4 acc[4] = {};
    if (s > 0) {
      // wait: all 32 blocks of this direction finished step s-1
      if (tid == 0) {
        const unsigned int tgt = 32u * (unsigned)s;
        while (__hip_atomic_load(cnt, __ATOMIC_RELAXED, __HIP_MEMORY_SCOPE_AGENT) < tgt) {}
      }
      __syncthreads();
      __threadfence();  // acquire: invalidate caches before reading peers' h
      const int tp = dir ? t + 1 : t - 1;
      const bf16* hp = hout + (size_t)tp * 64 * 1024 + dir * 512;
#pragma unroll 4
      for (int kt = 0; kt < 16; ++kt) {
#pragma unroll
        for (int mt = 0; mt < 4; ++mt) {
          bf16x8 afr = *(const bf16x8*)(hp + (size_t)(mt * 16 + lr) * 1024 + kt * 32 + lh * 8);
          acc[mt] = __builtin_amdgcn_mfma_f32_16x16x32_bf16(afr, wfrag[kt], acc[mt], 0, 0, 0);
        }
      }
    }
#pragma unroll
    for (int mt = 0; mt < 4; ++mt)
#pragma unroll
      for (int r = 0; r < 4; ++r) {
        bf16 pv; *(unsigned short*)&pv = pf[mt * 4 + r];
        float v = acc[mt][r] + bb + __bfloat162float(pv);
        xch[(wave * 64 + mt * 16 + lh * 4 + r) * 17 + lr] = v;
      }
    __syncthreads();
#pragma unroll
    for (int p = 0; p < 4; ++p) {
      int pid = tid + 256 * p;  // 1024 (batch,col) pairs
      int row = pid >> 4, col = pid & 15;
      float gi = xch[(0 * 64 + row) * 17 + col];
      float gf = xch[(1 * 64 + row) * 17 + col];
      float gg = xch[(2 * 64 + row) * 17 + col];
      float go = xch[(3 * 64 + row) * 17 + col];
      float c = cst[pid];
      float cn = sigm(gf) * c + sigm(gi) * tanh_(gg);
      cst[pid] = cn;
      float h = sigm(go) * tanh_(cn);
      hout[((size_t)t * 64 + row) * 1024 + dir * 512 + jb * 16 + col] = __float2bfloat16(h);
    }
    __syncthreads();
    __threadfence();  // release: push h writes to coherence point
    if (tid == 0) __hip_atomic_fetch_add(cnt, 1u, __ATOMIC_RELAXED, __HIP_MEMORY_SCOPE_AGENT);
    // prefetch pre for next step (hides under the next barrier spin)
    if (s < 255) {
      const int tn = dir ? t - 1 : t + 1;
      const bf16* pr = pre + (size_t)tn * 64 * 4096 + colg;
#pragma unroll
      for (int mt = 0; mt < 4; ++mt)
#pragma unroll
        for (int r = 0; r < 4; ++r)
          pf[mt * 4 + r] = *(const unsigned short*)(pr + (size_t)(mt * 16 + lh * 4 + r) * 4096);
    }
  }
}

// ---------------- emit projection: emit[16384][64] = h1 @ WoutB + bout, masked ----------------
__global__ __launch_bounds__(256) void emit_k(const bf16* __restrict__ h1, const bf16* __restrict__ wo,
                                              const float* __restrict__ bout, const int* __restrict__ x,
                                              float* __restrict__ emit) {
  const int tid = threadIdx.x, lane = tid & 63, wave = tid >> 6;
  const int lr = lane & 15, lh = lane >> 4;
  const int mb = blockIdx.x * 64 + wave * 16;
  f32x4 acc[4] = {};
  for (int kt = 0; kt < 32; ++kt) {
    bf16x8 a = *(const bf16x8*)(h1 + (size_t)(mb + lr) * 1024 + kt * 32 + lh * 8);
#pragma unroll
    for (int q = 0; q < 4; ++q) {
      bf16x8 b = *(const bf16x8*)(wo + ((size_t)(q * 32 + kt) * 64 + lane) * 8);
      acc[q] = __builtin_amdgcn_mfma_f32_16x16x32_bf16(a, b, acc[q], 0, 0, 0);
    }
  }
#pragma unroll
  for (int q = 0; q < 4; ++q)
#pragma unroll
    for (int r = 0; r < 4; ++r) {
      int row = mb + lh * 4 + r;
      int col = q * 16 + lr;
      int tt = row >> 6, bi = row & 63;
      float m = (x[bi * 256 + tt] > 0) ? 1.f : 0.f;
      emit[(size_t)row * 64 + col] = (acc[q][r] + bout[col]) * m;
    }
}

// ---------------- CRF forward + gold score, one block per batch element ----------------
__global__ __launch_bounds__(256) void crf_k(const float* __restrict__ emit, const float* __restrict__ trans,
                                             const int* __restrict__ x, const int* __restrict__ y0,
                                             float* __restrict__ out) {
  const int b = blockIdx.x, tid = threadIdx.x;
  __shared__ float tr[4096];
  __shared__ float sc[2][64];
  __shared__ float pm[4][64], ps[4][64];
  __shared__ float redw[4];
  for (int i = tid; i < 4096; i += 256) tr[i] = trans[i];
  if (tid < 64) sc[0][tid] = (tid == 2) ? 0.f : NEGV;  // SOS=2
  __syncthreads();
  {
    const int t = tid;
    const int tag = y0[b * 256 + t];
    const int prev = t ? y0[b * 256 + t - 1] : 2;
    const float m = (x[b * 256 + t] > 0) ? 1.f : 0.f;
    float g = emit[((size_t)t * 64 + b) * 64 + tag] + tr[tag * 64 + prev] * m;
    for (int o = 32; o; o >>= 1) g += __shfl_down(g, o, 64);
    if ((tid & 63) == 0) redw[tid >> 6] = g;
  }
  __syncthreads();
  const float gold = redw[0] + redw[1] + redw[2] + redw[3];
  const int j = tid & 63, kq = tid >> 6;
  int cur = 0;
  for (int t = 0; t < 256; ++t) {
    const float* trj = tr + j * 64 + kq * 16;
    const float* scc = sc[cur] + kq * 16;
    float v[16];
    float mx = -3.0e38f;
#pragma unroll
    for (int k = 0; k < 16; ++k) {
      v[k] = scc[k] + trj[k];
      mx = fmaxf(mx, v[k]);
    }
    float sm = 0.f;
#pragma unroll
    for (int k = 0; k < 16; ++k) sm += __expf(v[k] - mx);
    pm[kq][j] = mx;
    ps[kq][j] = sm;
    __syncthreads();
    if (kq == 0) {
      float M = fmaxf(fmaxf(pm[0][j], pm[1][j]), fmaxf(pm[2][j], pm[3][j]));
      float S = ps[0][j] * __expf(pm[0][j] - M) + ps[1][j] * __expf(pm[1][j] - M) +
                ps[2][j] * __expf(pm[2][j] - M) + ps[3][j] * __expf(pm[3][j] - M);
      float nv = M + __logf(S) + emit[((size_t)t * 64 + b) * 64 + j];
      sc[cur ^ 1][j] = (x[b * 256 + t] > 0) ? nv : sc[cur][j];
    }
    __syncthreads();
    cur ^= 1;
  }
  if (tid < 64) {
    float v2 = sc[cur][tid];
    float M = v2;
    for (int o = 32; o; o >>= 1) M = fmaxf(M, __shfl_xor(M, o, 64));
    float s2 = __expf(v2 - M);
    for (int o = 32; o; o >>= 1) s2 += __shfl_xor(s2, o, 64);
    if (tid == 0) out[b] = M + __logf(s2) - gold;
  }
}

// ---------------- launch ----------------
extern "C" void kernel_launch(void* const* d_in, const int* in_sizes, int n_in, void* d_out, int out_size,
                              void* d_ws, size_t ws_size, hipStream_t stream) {
  (void)in_sizes; (void)n_in; (void)out_size; (void)ws_size;
  const int* x = (const int*)d_in[0];
  const int* y0 = (const int*)d_in[1];
  const float* embed = (const float*)d_in[2];
  const float* Wih0f = (const float*)d_in[3];
  const float* Whh0f = (const float*)d_in[4];
  const float* b0f = (const float*)d_in[5];
  const float* Wih0b = (const float*)d_in[6];
  const float* Whh0b = (const float*)d_in[7];
  const float* b0b = (const float*)d_in[8];
  const float* Wih1f = (const float*)d_in[9];
  const float* Whh1f = (const float*)d_in[10];
  const float* b1f = (const float*)d_in[11];
  const float* Wih1b = (const float*)d_in[12];
  const float* Whh1b = (const float*)d_in[13];
  const float* b1b = (const float*)d_in[14];
  const float* Wout = (const float*)d_in[15];
  const float* bout = (const float*)d_in[16];
  const float* trans = (const float*)d_in[17];

  char* p = (char*)d_ws;
  auto take = [&](size_t n) { char* r = p; p += (n + 255) & ~(size_t)255; return r; };
  unsigned int* bars = (unsigned int*)take(4 * sizeof(unsigned int));  // [l0 f,b, l1 f,b]
  bf16* xs = (bf16*)take(16384ull * 320 * 2);
  bf16* pre = (bf16*)take(16384ull * 4096 * 2);
  bf16* h0 = (bf16*)take(16384ull * 1024 * 2);
  bf16* h1 = (bf16*)take(16384ull * 1024 * 2);
  float* emitb = (float*)take(16384ull * 64 * 4);
  bf16* W0B = (bf16*)take(4096ull * 320 * 2);
  bf16* W1B = (bf16*)take(4096ull * 1024 * 2);
  bf16* WhhB = (bf16*)take(4ull * 1048576 * 2);
  bf16* WoB = (bf16*)take(64ull * 1024 * 2);
  float* bias0 = (float*)take(4096 * 4);
  float* bias1 = (float*)take(4096 * 4);

  hipMemsetAsync(bars, 0, 4 * sizeof(unsigned int), stream);
  hipLaunchKernelGGL(pack_w0, dim3(5120), dim3(256), 0, stream, Wih0f, Wih0b, W0B);
  hipLaunchKernelGGL(pack_whh, dim3(4096), dim3(256), 0, stream, Whh0f, WhhB + 0ull * 1048576);
  hipLaunchKernelGGL(pack_whh, dim3(4096), dim3(256), 0, stream, Whh0b, WhhB + 1ull * 1048576);
  hipLaunchKernelGGL(pack_whh, dim3(4096), dim3(256), 0, stream, Whh1f, WhhB + 2ull * 1048576);
  hipLaunchKernelGGL(pack_whh, dim3(4096), dim3(256), 0, stream, Whh1b, WhhB + 3ull * 1048576);
  hipLaunchKernelGGL(pack_w1, dim3(16384), dim3(256), 0, stream, Wih1f, Wih1b, W1B);
  hipLaunchKernelGGL(pack_wout, dim3(256), dim3(256), 0, stream, Wout, WoB);
  hipLaunchKernelGGL(pack_bias, dim3(16), dim3(256), 0, stream, b0f, b0b, bias0);
  hipLaunchKernelGGL(pack_bias, dim3(16), dim3(256), 0, stream, b1f, b1b, bias1);
  hipLaunchKernelGGL(embed_k, dim3(20480), dim3(256), 0, stream, x, embed, xs);

  hipLaunchKernelGGL(gemm_nt, dim3(256, 16), dim3(256), 0, stream, xs, W0B, pre, 320, 10);
  {
    const bf16* a0 = pre; const bf16* a1 = WhhB; const float* a2 = bias0; bf16* a3 = h0;
    unsigned int* a4 = bars;
    void* args[] = {&a0, &a1, &a2, &a3, &a4};
    hipLaunchCooperativeKernel((void*)lstm_layer, dim3(32, 2), dim3(256), args, 0, stream);
  }
  hipLaunchKernelGGL(gemm_nt, dim3(256, 16), dim3(256), 0, stream, h0, W1B, pre, 1024, 32);
  {
    const bf16* a0 = pre; const bf16* a1 = WhhB + 2ull * 1048576; const float* a2 = bias1; bf16* a3 = h1;
    unsigned int* a4 = bars + 2;
    void* args[] = {&a0, &a1, &a2, &a3, &a4};
    hipLaunchCooperativeKernel((void*)lstm_layer, dim3(32, 2), dim3(256), args, 0, stream);
  }
  hipLaunchKernelGGL(emit_k, dim3(256), dim3(256), 0, stream, h1, WoB, bout, x, emitb);
  hipLaunchKernelGGL(crf_k, dim3(64), dim3(256), 0, stream, emitb, trans, x, y0, (float*)d_out);
}

// Round 3
// 10628.978 us; speedup vs baseline: 1.2596x; 1.2596x over previous
//
#include <hip/hip_runtime.h>
#include <hip/hip_bf16.h>

typedef short bf16x8 __attribute__((ext_vector_type(8)));
typedef float f32x4 __attribute__((ext_vector_type(4)));
typedef __hip_bfloat16 bf16;

#define NEGV -10000.0f

// Problem dims: B=64, T=256, E=300, H=500, K=64(tags), V=32000
// Padded: Ep=320, Hp=512, layer-1 input 2*Hp=1024, gate width 4096 = 2dir*4gate*512

__device__ __forceinline__ float sigm(float v) { return 1.0f / (1.0f + __expf(-v)); }
__device__ __forceinline__ float tanh_(float v) { float e = __expf(2.0f * v); return 1.0f - 2.0f / (e + 1.0f); }

// ---------------- weight packing into MFMA fragment-linear layout ----------------
// B-frag layout: dst[((nt*Kt + kt)*64 + lane)*8 + u] = B[kt*32 + (lane>>4)*8 + u][nt*16 + (lane&15)]

__global__ __launch_bounds__(256) void pack_w0(const float* __restrict__ wf, const float* __restrict__ wb,
                                               bf16* __restrict__ dst) {
  int idx = blockIdx.x * 256 + threadIdx.x;            // 4096*320 = 1310720
  int u = idx & 7, lane = (idx >> 3) & 63, rem = idx >> 9;
  int kt = rem % 10, nt = rem / 10;
  int n = (nt << 4) + (lane & 15), k = (kt << 5) + ((lane >> 4) << 3) + u;
  int d = n >> 11, g = (n >> 9) & 3, j = n & 511;
  float v = 0.f;
  if (j < 500 && k < 300) v = (d ? wb : wf)[(g * 500 + j) * 300 + k];
  dst[idx] = __float2bfloat16(v);
}

__global__ __launch_bounds__(256) void pack_whh(const float* __restrict__ w, bf16* __restrict__ dst) {
  int idx = blockIdx.x * 256 + threadIdx.x;            // 2048*512 = 1048576
  int u = idx & 7, lane = (idx >> 3) & 63, rem = idx >> 9;
  int kt = rem & 15, nt = rem >> 4;
  int n = (nt << 4) + (lane & 15), k = (kt << 5) + ((lane >> 4) << 3) + u;
  int g = n >> 9, j = n & 511;
  float v = 0.f;
  if (j < 500 && k < 500) v = w[(g * 500 + j) * 500 + k];
  dst[idx] = __float2bfloat16(v);
}

__global__ __launch_bounds__(256) void pack_w1(const float* __restrict__ wf, const float* __restrict__ wb,
                                               bf16* __restrict__ dst) {
  int idx = blockIdx.x * 256 + threadIdx.x;            // 4096*1024 = 4194304
  int u = idx & 7, lane = (idx >> 3) & 63, rem = idx >> 9;
  int kt = rem & 31, nt = rem >> 5;
  int n = (nt << 4) + (lane & 15), k = (kt << 5) + ((lane >> 4) << 3) + u;
  int d = n >> 11, g = (n >> 9) & 3, j = n & 511;
  int kk = k & 511;
  int ks = (k < 512) ? kk : 500 + kk;
  float v = 0.f;
  if (j < 500 && kk < 500) v = (d ? wb : wf)[(g * 500 + j) * 1000 + ks];
  dst[idx] = __float2bfloat16(v);
}

__global__ __launch_bounds__(256) void pack_wout(const float* __restrict__ w, bf16* __restrict__ dst) {
  int idx = blockIdx.x * 256 + threadIdx.x;            // 4*32*512 = 65536
  int u = idx & 7, lane = (idx >> 3) & 63, rem = idx >> 9;
  int kt = rem & 31, nt = rem >> 5;
  int n = (nt << 4) + (lane & 15), k = (kt << 5) + ((lane >> 4) << 3) + u;
  int kk = k & 511;
  int ks = (k < 512) ? kk : 500 + kk;
  float v = 0.f;
  if (kk < 500) v = w[n * 1000 + ks];
  dst[idx] = __float2bfloat16(v);
}

__global__ __launch_bounds__(256) void pack_bias(const float* __restrict__ bf_, const float* __restrict__ bb_,
                                                 float* __restrict__ dst) {
  int idx = blockIdx.x * 256 + threadIdx.x;            // 4096
  int d = idx >> 11, g = (idx >> 9) & 3, j = idx & 511;
  dst[idx] = (j < 500) ? (d ? bb_ : bf_)[g * 500 + j] : 0.f;
}

// ---------------- embedding gather -> bf16 [T*B][320] ----------------
__global__ __launch_bounds__(256) void embed_k(const int* __restrict__ x, const float* __restrict__ em,
                                               bf16* __restrict__ xs) {
  int idx = blockIdx.x * 256 + threadIdx.x;            // 16384*320
  int e = idx % 320;
  int row = idx / 320;
  int t = row >> 6, b = row & 63;
  float v = 0.f;
  if (e < 300) {
    int xv = x[b * 256 + t];
    v = em[(size_t)xv * 300 + e];
  }
  xs[idx] = __float2bfloat16(v);
}

// ---------------- generic MFMA GEMM: C[16384][4096] = A[16384][Kdim] @ Bfrag ----------------
__global__ __launch_bounds__(256) void gemm_nt(const bf16* __restrict__ A, const bf16* __restrict__ Bf,
                                               bf16* __restrict__ C, int Kdim, int Kt) {
  const int lane = threadIdx.x & 63, wave = threadIdx.x >> 6;
  const int lr = lane & 15, lh = lane >> 4;
  const int mb = blockIdx.x * 64;
  const int ntb = blockIdx.y * 16 + wave * 4;
  f32x4 acc[4][4] = {};
  for (int kt = 0; kt < Kt; ++kt) {
    bf16x8 a[4], b[4];
#pragma unroll
    for (int mt = 0; mt < 4; ++mt)
      a[mt] = *(const bf16x8*)(A + (size_t)(mb + mt * 16 + lr) * Kdim + kt * 32 + lh * 8);
#pragma unroll
    for (int q = 0; q < 4; ++q)
      b[q] = *(const bf16x8*)(Bf + ((size_t)(ntb + q) * Kt + kt) * 512 + lane * 8);
#pragma unroll
    for (int mt = 0; mt < 4; ++mt)
#pragma unroll
      for (int q = 0; q < 4; ++q)
        acc[mt][q] = __builtin_amdgcn_mfma_f32_16x16x32_bf16(a[mt], b[q], acc[mt][q], 0, 0, 0);
  }
#pragma unroll
  for (int mt = 0; mt < 4; ++mt)
#pragma unroll
    for (int q = 0; q < 4; ++q)
#pragma unroll
      for (int r = 0; r < 4; ++r) {
        int row = mb + mt * 16 + lh * 4 + r;
        int col = (ntb + q) * 16 + lr;
        C[(size_t)row * 4096 + col] = __float2bfloat16(acc[mt][q][r]);
      }
}

// ---------------- cooperative bidirectional LSTM layer ----------------
// grid(32 jb-tiles, 2 dirs), 256 threads (wave = gate). No whole-cache fences:
// h is exchanged via 8-byte relaxed AGENT-scope atomic load/store (sc0/sc1 coherent
// at L3), release = s_waitcnt vmcnt(0) + __syncthreads before the flag atomicAdd.
__global__ __launch_bounds__(256) void lstm_layer(const bf16* __restrict__ pre, const bf16* __restrict__ whh,
                                                  const float* __restrict__ bias, bf16* __restrict__ hout,
                                                  unsigned int* __restrict__ barcnt) {
  const int tid = threadIdx.x, lane = tid & 63, wave = tid >> 6;
  const int lr = lane & 15, lh = lane >> 4;
  const int jb = blockIdx.x, dir = blockIdx.y;
  unsigned int* cnt = barcnt + dir;
  __shared__ float xch[4 * 64 * 17];  // [gate][batch][16 cols], stride-17 pad
  __shared__ float cst[64 * 16];      // c-state fp32, persistent across steps
  for (int i = tid; i < 1024; i += 256) cst[i] = 0.f;
  const int colg = dir * 2048 + wave * 512 + jb * 16 + lr;
  const float bb = bias[colg];
  const bf16* wbase = whh + ((size_t)(dir * 128 + wave * 32 + jb) * 16) * 512 + lane * 8;

  // preload recurrent weights into registers (16 frags = 64 VGPRs)
  bf16x8 wfrag[16];
#pragma unroll
  for (int kt = 0; kt < 16; ++kt) wfrag[kt] = *(const bf16x8*)(wbase + kt * 512);

  // prefetch pre for first step
  unsigned short pf[16];
  {
    const bf16* pr = pre + (size_t)(dir ? 255 : 0) * 64 * 4096 + colg;
#pragma unroll
    for (int mt = 0; mt < 4; ++mt)
#pragma unroll
      for (int r = 0; r < 4; ++r)
        pf[mt * 4 + r] = *(const unsigned short*)(pr + (size_t)(mt * 16 + lh * 4 + r) * 4096);
  }

  const int srow = tid >> 2, sq = tid & 3;  // h-store mapping: one 4-col quad per thread

  for (int s = 0; s < 256; ++s) {
    const int t = dir ? 255 - s : s;
    f32x4 acc[4] = {};
    if (s > 0) {
      // wait: all 32 blocks of this direction finished step s-1
      if (tid == 0) {
        const unsigned int tgt = 32u * (unsigned)s;
        while (__hip_atomic_load(cnt, __ATOMIC_RELAXED, __HIP_MEMORY_SCOPE_AGENT) < tgt) {}
      }
      __syncthreads();
      const int tp = dir ? t + 1 : t - 1;
      const bf16* hp = hout + (size_t)tp * 64 * 1024 + dir * 512;
#pragma unroll 4
      for (int kt = 0; kt < 16; ++kt) {
#pragma unroll
        for (int mt = 0; mt < 4; ++mt) {
          const unsigned long long* hq =
              (const unsigned long long*)(hp + (size_t)(mt * 16 + lr) * 1024 + kt * 32 + lh * 8);
          union { unsigned long long q[2]; bf16x8 v; } u;
          u.q[0] = __hip_atomic_load(hq, __ATOMIC_RELAXED, __HIP_MEMORY_SCOPE_AGENT);
          u.q[1] = __hip_atomic_load(hq + 1, __ATOMIC_RELAXED, __HIP_MEMORY_SCOPE_AGENT);
          acc[mt] = __builtin_amdgcn_mfma_f32_16x16x32_bf16(u.v, wfrag[kt], acc[mt], 0, 0, 0);
        }
      }
    }
#pragma unroll
    for (int mt = 0; mt < 4; ++mt)
#pragma unroll
      for (int r = 0; r < 4; ++r) {
        bf16 pv; *(unsigned short*)&pv = pf[mt * 4 + r];
        float v = acc[mt][r] + bb + __bfloat162float(pv);
        xch[(wave * 64 + mt * 16 + lh * 4 + r) * 17 + lr] = v;
      }
    __syncthreads();
    {
      unsigned long long pk = 0;
#pragma unroll
      for (int i = 0; i < 4; ++i) {
        int col = sq * 4 + i;
        float gi = xch[(0 * 64 + srow) * 17 + col];
        float gf = xch[(1 * 64 + srow) * 17 + col];
        float gg = xch[(2 * 64 + srow) * 17 + col];
        float go = xch[(3 * 64 + srow) * 17 + col];
        float c = cst[srow * 16 + col];
        float cn = sigm(gf) * c + sigm(gi) * tanh_(gg);
        cst[srow * 16 + col] = cn;
        float h = sigm(go) * tanh_(cn);
        bf16 hb = __float2bfloat16(h);
        pk |= (unsigned long long)(*(unsigned short*)&hb) << (16 * i);
      }
      unsigned long long* hq =
          (unsigned long long*)(hout + ((size_t)t * 64 + srow) * 1024 + dir * 512 + jb * 16 + sq * 4);
      __hip_atomic_store(hq, pk, __ATOMIC_RELAXED, __HIP_MEMORY_SCOPE_AGENT);
    }
    // release: drain own coherent stores, join waves, then bump the flag
    asm volatile("s_waitcnt vmcnt(0)" ::: "memory");
    __syncthreads();
    if (tid == 0) __hip_atomic_fetch_add(cnt, 1u, __ATOMIC_RELAXED, __HIP_MEMORY_SCOPE_AGENT);
    // prefetch pre for next step (hides under the next barrier spin)
    if (s < 255) {
      const int tn = dir ? t - 1 : t + 1;
      const bf16* pr = pre + (size_t)tn * 64 * 4096 + colg;
#pragma unroll
      for (int mt = 0; mt < 4; ++mt)
#pragma unroll
        for (int r = 0; r < 4; ++r)
          pf[mt * 4 + r] = *(const unsigned short*)(pr + (size_t)(mt * 16 + lh * 4 + r) * 4096);
    }
  }
}

// ---------------- emit projection: emit[16384][64] = h1 @ WoutB + bout, masked ----------------
__global__ __launch_bounds__(256) void emit_k(const bf16* __restrict__ h1, const bf16* __restrict__ wo,
                                              const float* __restrict__ bout, const int* __restrict__ x,
                                              float* __restrict__ emit) {
  const int tid = threadIdx.x, lane = tid & 63, wave = tid >> 6;
  const int lr = lane & 15, lh = lane >> 4;
  const int mb = blockIdx.x * 64 + wave * 16;
  f32x4 acc[4] = {};
  for (int kt = 0; kt < 32; ++kt) {
    bf16x8 a = *(const bf16x8*)(h1 + (size_t)(mb + lr) * 1024 + kt * 32 + lh * 8);
#pragma unroll
    for (int q = 0; q < 4; ++q) {
      bf16x8 b = *(const bf16x8*)(wo + ((size_t)(q * 32 + kt) * 64 + lane) * 8);
      acc[q] = __builtin_amdgcn_mfma_f32_16x16x32_bf16(a, b, acc[q], 0, 0, 0);
    }
  }
#pragma unroll
  for (int q = 0; q < 4; ++q)
#pragma unroll
    for (int r = 0; r < 4; ++r) {
      int row = mb + lh * 4 + r;
      int col = q * 16 + lr;
      int tt = row >> 6, bi = row & 63;
      float m = (x[bi * 256 + tt] > 0) ? 1.f : 0.f;
      emit[(size_t)row * 64 + col] = (acc[q][r] + bout[col]) * m;
    }
}

// ---------------- CRF forward + gold score, one block per batch element ----------------
__global__ __launch_bounds__(256) void crf_k(const float* __restrict__ emit, const float* __restrict__ trans,
                                             const int* __restrict__ x, const int* __restrict__ y0,
                                             float* __restrict__ out) {
  const int b = blockIdx.x, tid = threadIdx.x;
  __shared__ float tr[4096];
  __shared__ float sc[2][64];
  __shared__ float pm[4][64], ps[4][64];
  __shared__ float redw[4];
  for (int i = tid; i < 4096; i += 256) tr[i] = trans[i];
  if (tid < 64) sc[0][tid] = (tid == 2) ? 0.f : NEGV;  // SOS=2
  __syncthreads();
  {
    const int t = tid;
    const int tag = y0[b * 256 + t];
    const int prev = t ? y0[b * 256 + t - 1] : 2;
    const float m = (x[b * 256 + t] > 0) ? 1.f : 0.f;
    float g = emit[((size_t)t * 64 + b) * 64 + tag] + tr[tag * 64 + prev] * m;
    for (int o = 32; o; o >>= 1) g += __shfl_down(g, o, 64);
    if ((tid & 63) == 0) redw[tid >> 6] = g;
  }
  __syncthreads();
  const float gold = redw[0] + redw[1] + redw[2] + redw[3];
  const int j = tid & 63, kq = tid >> 6;
  int cur = 0;
  for (int t = 0; t < 256; ++t) {
    const float* trj = tr + j * 64 + kq * 16;
    const float* scc = sc[cur] + kq * 16;
    float v[16];
    float mx = -3.0e38f;
#pragma unroll
    for (int k = 0; k < 16; ++k) {
      v[k] = scc[k] + trj[k];
      mx = fmaxf(mx, v[k]);
    }
    float sm = 0.f;
#pragma unroll
    for (int k = 0; k < 16; ++k) sm += __expf(v[k] - mx);
    pm[kq][j] = mx;
    ps[kq][j] = sm;
    __syncthreads();
    if (kq == 0) {
      float M = fmaxf(fmaxf(pm[0][j], pm[1][j]), fmaxf(pm[2][j], pm[3][j]));
      float S = ps[0][j] * __expf(pm[0][j] - M) + ps[1][j] * __expf(pm[1][j] - M) +
                ps[2][j] * __expf(pm[2][j] - M) + ps[3][j] * __expf(pm[3][j] - M);
      float nv = M + __logf(S) + emit[((size_t)t * 64 + b) * 64 + j];
      sc[cur ^ 1][j] = (x[b * 256 + t] > 0) ? nv : sc[cur][j];
    }
    __syncthreads();
    cur ^= 1;
  }
  if (tid < 64) {
    float v2 = sc[cur][tid];
    float M = v2;
    for (int o = 32; o; o >>= 1) M = fmaxf(M, __shfl_xor(M, o, 64));
    float s2 = __expf(v2 - M);
    for (int o = 32; o; o >>= 1) s2 += __shfl_xor(s2, o, 64);
    if (tid == 0) out[b] = M + __logf(s2) - gold;
  }
}

// ---------------- launch ----------------
extern "C" void kernel_launch(void* const* d_in, const int* in_sizes, int n_in, void* d_out, int out_size,
                              void* d_ws, size_t ws_size, hipStream_t stream) {
  (void)in_sizes; (void)n_in; (void)out_size; (void)ws_size;
  const int* x = (const int*)d_in[0];
  const int* y0 = (const int*)d_in[1];
  const float* embed = (const float*)d_in[2];
  const float* Wih0f = (const float*)d_in[3];
  const float* Whh0f = (const float*)d_in[4];
  const float* b0f = (const float*)d_in[5];
  const float* Wih0b = (const float*)d_in[6];
  const float* Whh0b = (const float*)d_in[7];
  const float* b0b = (const float*)d_in[8];
  const float* Wih1f = (const float*)d_in[9];
  const float* Whh1f = (const float*)d_in[10];
  const float* b1f = (const float*)d_in[11];
  const float* Wih1b = (const float*)d_in[12];
  const float* Whh1b = (const float*)d_in[13];
  const float* b1b = (const float*)d_in[14];
  const float* Wout = (const float*)d_in[15];
  const float* bout = (const float*)d_in[16];
  const float* trans = (const float*)d_in[17];

  char* p = (char*)d_ws;
  auto take = [&](size_t n) { char* r = p; p += (n + 255) & ~(size_t)255; return r; };
  unsigned int* bars = (unsigned int*)take(4 * sizeof(unsigned int));  // [l0 f,b, l1 f,b]
  bf16* xs = (bf16*)take(16384ull * 320 * 2);
  bf16* pre = (bf16*)take(16384ull * 4096 * 2);
  bf16* h0 = (bf16*)take(16384ull * 1024 * 2);
  bf16* h1 = (bf16*)take(16384ull * 1024 * 2);
  float* emitb = (float*)take(16384ull * 64 * 4);
  bf16* W0B = (bf16*)take(4096ull * 320 * 2);
  bf16* W1B = (bf16*)take(4096ull * 1024 * 2);
  bf16* WhhB = (bf16*)take(4ull * 1048576 * 2);
  bf16* WoB = (bf16*)take(64ull * 1024 * 2);
  float* bias0 = (float*)take(4096 * 4);
  float* bias1 = (float*)take(4096 * 4);

  hipMemsetAsync(bars, 0, 4 * sizeof(unsigned int), stream);
  hipLaunchKernelGGL(pack_w0, dim3(5120), dim3(256), 0, stream, Wih0f, Wih0b, W0B);
  hipLaunchKernelGGL(pack_whh, dim3(4096), dim3(256), 0, stream, Whh0f, WhhB + 0ull * 1048576);
  hipLaunchKernelGGL(pack_whh, dim3(4096), dim3(256), 0, stream, Whh0b, WhhB + 1ull * 1048576);
  hipLaunchKernelGGL(pack_whh, dim3(4096), dim3(256), 0, stream, Whh1f, WhhB + 2ull * 1048576);
  hipLaunchKernelGGL(pack_whh, dim3(4096), dim3(256), 0, stream, Whh1b, WhhB + 3ull * 1048576);
  hipLaunchKernelGGL(pack_w1, dim3(16384), dim3(256), 0, stream, Wih1f, Wih1b, W1B);
  hipLaunchKernelGGL(pack_wout, dim3(256), dim3(256), 0, stream, Wout, WoB);
  hipLaunchKernelGGL(pack_bias, dim3(16), dim3(256), 0, stream, b0f, b0b, bias0);
  hipLaunchKernelGGL(pack_bias, dim3(16), dim3(256), 0, stream, b1f, b1b, bias1);
  hipLaunchKernelGGL(embed_k, dim3(20480), dim3(256), 0, stream, x, embed, xs);

  hipLaunchKernelGGL(gemm_nt, dim3(256, 16), dim3(256), 0, stream, xs, W0B, pre, 320, 10);
  {
    const bf16* a0 = pre; const bf16* a1 = WhhB; const float* a2 = bias0; bf16* a3 = h0;
    unsigned int* a4 = bars;
    void* args[] = {&a0, &a1, &a2, &a3, &a4};
    hipLaunchCooperativeKernel((void*)lstm_layer, dim3(32, 2), dim3(256), args, 0, stream);
  }
  hipLaunchKernelGGL(gemm_nt, dim3(256, 16), dim3(256), 0, stream, h0, W1B, pre, 1024, 32);
  {
    const bf16* a0 = pre; const bf16* a1 = WhhB + 2ull * 1048576; const float* a2 = bias1; bf16* a3 = h1;
    unsigned int* a4 = bars + 2;
    void* args[] = {&a0, &a1, &a2, &a3, &a4};
    hipLaunchCooperativeKernel((void*)lstm_layer, dim3(32, 2), dim3(256), args, 0, stream);
  }
  hipLaunchKernelGGL(emit_k, dim3(256), dim3(256), 0, stream, h1, WoB, bout, x, emitb);
  hipLaunchKernelGGL(crf_k, dim3(64), dim3(256), 0, stream, emitb, trans, x, y0, (float*)d_out);
}

// Round 4
// 8902.222 us; speedup vs baseline: 1.5039x; 1.1940x over previous
//
#include <hip/hip_runtime.h>
#include <hip/hip_bf16.h>

typedef short bf16x8 __attribute__((ext_vector_type(8)));
typedef float f32x4 __attribute__((ext_vector_type(4)));
typedef __hip_bfloat16 bf16;
typedef unsigned long long ull;

#define NEGV -10000.0f

// Problem dims: B=64, T=256, E=300, H=500, K=64(tags), V=32000
// Padded: Ep=320, Hp=512, layer-1 input 2*Hp=1024, gate width 4096 = 2dir*4gate*512

__device__ __forceinline__ float sigm(float v) { return 1.0f / (1.0f + __expf(-v)); }
__device__ __forceinline__ float tanh_(float v) { float e = __expf(2.0f * v); return 1.0f - 2.0f / (e + 1.0f); }

// ---------------- weight packing into MFMA fragment-linear layout ----------------
// B-frag layout: dst[((nt*Kt + kt)*64 + lane)*8 + u] = B[kt*32 + (lane>>4)*8 + u][nt*16 + (lane&15)]

__global__ __launch_bounds__(256) void pack_w0(const float* __restrict__ wf, const float* __restrict__ wb,
                                               bf16* __restrict__ dst) {
  int idx = blockIdx.x * 256 + threadIdx.x;            // 4096*320 = 1310720
  int u = idx & 7, lane = (idx >> 3) & 63, rem = idx >> 9;
  int kt = rem % 10, nt = rem / 10;
  int n = (nt << 4) + (lane & 15), k = (kt << 5) + ((lane >> 4) << 3) + u;
  int d = n >> 11, g = (n >> 9) & 3, j = n & 511;
  float v = 0.f;
  if (j < 500 && k < 300) v = (d ? wb : wf)[(g * 500 + j) * 300 + k];
  dst[idx] = __float2bfloat16(v);
}

__global__ __launch_bounds__(256) void pack_whh(const float* __restrict__ w, bf16* __restrict__ dst) {
  int idx = blockIdx.x * 256 + threadIdx.x;            // 2048*512 = 1048576
  int u = idx & 7, lane = (idx >> 3) & 63, rem = idx >> 9;
  int kt = rem & 15, nt = rem >> 4;
  int n = (nt << 4) + (lane & 15), k = (kt << 5) + ((lane >> 4) << 3) + u;
  int g = n >> 9, j = n & 511;
  float v = 0.f;
  if (j < 500 && k < 500) v = w[(g * 500 + j) * 500 + k];
  dst[idx] = __float2bfloat16(v);
}

__global__ __launch_bounds__(256) void pack_w1(const float* __restrict__ wf, const float* __restrict__ wb,
                                               bf16* __restrict__ dst) {
  int idx = blockIdx.x * 256 + threadIdx.x;            // 4096*1024 = 4194304
  int u = idx & 7, lane = (idx >> 3) & 63, rem = idx >> 9;
  int kt = rem & 31, nt = rem >> 5;
  int n = (nt << 4) + (lane & 15), k = (kt << 5) + ((lane >> 4) << 3) + u;
  int d = n >> 11, g = (n >> 9) & 3, j = n & 511;
  int kk = k & 511;
  int ks = (k < 512) ? kk : 500 + kk;
  float v = 0.f;
  if (j < 500 && kk < 500) v = (d ? wb : wf)[(g * 500 + j) * 1000 + ks];
  dst[idx] = __float2bfloat16(v);
}

__global__ __launch_bounds__(256) void pack_wout(const float* __restrict__ w, bf16* __restrict__ dst) {
  int idx = blockIdx.x * 256 + threadIdx.x;            // 4*32*512 = 65536
  int u = idx & 7, lane = (idx >> 3) & 63, rem = idx >> 9;
  int kt = rem & 31, nt = rem >> 5;
  int n = (nt << 4) + (lane & 15), k = (kt << 5) + ((lane >> 4) << 3) + u;
  int kk = k & 511;
  int ks = (k < 512) ? kk : 500 + kk;
  float v = 0.f;
  if (kk < 500) v = w[n * 1000 + ks];
  dst[idx] = __float2bfloat16(v);
}

__global__ __launch_bounds__(256) void pack_bias(const float* __restrict__ bf_, const float* __restrict__ bb_,
                                                 float* __restrict__ dst) {
  int idx = blockIdx.x * 256 + threadIdx.x;            // 4096
  int d = idx >> 11, g = (idx >> 9) & 3, j = idx & 511;
  dst[idx] = (j < 500) ? (d ? bb_ : bf_)[g * 500 + j] : 0.f;
}

// ---------------- embedding gather -> bf16 [T*B][320] ----------------
__global__ __launch_bounds__(256) void embed_k(const int* __restrict__ x, const float* __restrict__ em,
                                               bf16* __restrict__ xs) {
  int idx = blockIdx.x * 256 + threadIdx.x;            // 16384*320
  int e = idx % 320;
  int row = idx / 320;
  int t = row >> 6, b = row & 63;
  float v = 0.f;
  if (e < 300) {
    int xv = x[b * 256 + t];
    v = em[(size_t)xv * 300 + e];
  }
  xs[idx] = __float2bfloat16(v);
}

// ---------------- generic MFMA GEMM: C[16384][4096] = A[16384][Kdim] @ Bfrag ----------------
__global__ __launch_bounds__(256) void gemm_nt(const bf16* __restrict__ A, const bf16* __restrict__ Bf,
                                               bf16* __restrict__ C, int Kdim, int Kt) {
  const int lane = threadIdx.x & 63, wave = threadIdx.x >> 6;
  const int lr = lane & 15, lh = lane >> 4;
  const int mb = blockIdx.x * 64;
  const int ntb = blockIdx.y * 16 + wave * 4;
  f32x4 acc[4][4] = {};
  for (int kt = 0; kt < Kt; ++kt) {
    bf16x8 a[4], b[4];
#pragma unroll
    for (int mt = 0; mt < 4; ++mt)
      a[mt] = *(const bf16x8*)(A + (size_t)(mb + mt * 16 + lr) * Kdim + kt * 32 + lh * 8);
#pragma unroll
    for (int q = 0; q < 4; ++q)
      b[q] = *(const bf16x8*)(Bf + ((size_t)(ntb + q) * Kt + kt) * 512 + lane * 8);
#pragma unroll
    for (int mt = 0; mt < 4; ++mt)
#pragma unroll
      for (int q = 0; q < 4; ++q)
        acc[mt][q] = __builtin_amdgcn_mfma_f32_16x16x32_bf16(a[mt], b[q], acc[mt][q], 0, 0, 0);
  }
#pragma unroll
  for (int mt = 0; mt < 4; ++mt)
#pragma unroll
    for (int q = 0; q < 4; ++q)
#pragma unroll
      for (int r = 0; r < 4; ++r) {
        int row = mb + mt * 16 + lh * 4 + r;
        int col = (ntb + q) * 16 + lr;
        C[(size_t)row * 4096 + col] = __float2bfloat16(acc[mt][q][r]);
      }
}

// ---------------- cooperative bidirectional LSTM layer ----------------
// grid(32 jb-tiles, 2 dirs), 256 threads (wave = gate). Slot-flag barrier:
// producer jb stores epoch s+1 to its own flag word (no RMW); consumers poll all
// 32 slots with one vector load across lanes + __all ballot. h exchanged via 8-byte
// relaxed AGENT-scope atomic load/store (coherent at L3).
// LDSH=1: the 64KB h tile is staged ONCE per block into XOR-swizzled LDS by all
// 256 threads cooperatively, then MFMA A-frags come from LDS (cuts 4x-redundant
// L3 reads). LDSH=0: R3-style per-wave direct atomic loads.
template <int LDSH>
__global__ __launch_bounds__(256) void lstm_layer(const bf16* __restrict__ pre, const bf16* __restrict__ whh,
                                                  const float* __restrict__ bias, bf16* __restrict__ hout,
                                                  unsigned int* __restrict__ flags) {
  const int tid = threadIdx.x, lane = tid & 63, wave = tid >> 6;
  const int lr = lane & 15, lh = lane >> 4;
  const int jb = blockIdx.x, dir = blockIdx.y;
  unsigned int* flg = flags + dir * 32;       // this direction's 32 slots
  unsigned int* myflg = flg + jb;
  __shared__ ull hlds[LDSH ? 8192 : 1];       // 64KB h tile (V1 only)
  __shared__ float xch[4 * 64 * 17];          // [gate][batch][16 cols], stride-17 pad
  __shared__ float cst[64 * 16];              // c-state fp32, persistent across steps
  for (int i = tid; i < 1024; i += 256) cst[i] = 0.f;
  const int colg = dir * 2048 + wave * 512 + jb * 16 + lr;
  const float bb = bias[colg];
  const bf16* wbase = whh + ((size_t)(dir * 128 + wave * 32 + jb) * 16) * 512 + lane * 8;

  // preload recurrent weights into registers (16 frags = 64 VGPRs)
  bf16x8 wfrag[16];
#pragma unroll
  for (int kt = 0; kt < 16; ++kt) wfrag[kt] = *(const bf16x8*)(wbase + kt * 512);

  // prefetch pre for first step
  unsigned short pf[16];
  {
    const bf16* pr = pre + (size_t)(dir ? 255 : 0) * 64 * 4096 + colg;
#pragma unroll
    for (int mt = 0; mt < 4; ++mt)
#pragma unroll
      for (int r = 0; r < 4; ++r)
        pf[mt * 4 + r] = *(const unsigned short*)(pr + (size_t)(mt * 16 + lh * 4 + r) * 4096);
  }

  const int srow = tid >> 2, sq = tid & 3;  // h-store mapping: one 4-col quad per thread

  for (int s = 0; s < 256; ++s) {
    const int t = dir ? 255 - s : s;
    f32x4 acc[4] = {};
    if (s > 0) {
      // wait: all 32 producer blocks of this direction finished step s-1.
      // One vector load covers all 32 slots (lanes 32-63 duplicate 0-31).
      for (;;) {
        unsigned int v = __hip_atomic_load(flg + (lane & 31), __ATOMIC_RELAXED, __HIP_MEMORY_SCOPE_AGENT);
        if (__all((int)(v >= (unsigned int)s))) break;
      }
      const int tp = dir ? t + 1 : t - 1;
      const bf16* hp = hout + (size_t)tp * 64 * 1024 + dir * 512;
      if (LDSH) {
        // cooperative single-copy stage: 8192 ull = 64KB, 32 per thread, coalesced.
        // LDS XOR swizzle on ull index: idx ^ ((row&7)<<1)  (byte bit-4 <- row bits)
#pragma unroll
        for (int i = 0; i < 32; ++i) {
          int u = i * 256 + tid;
          int row = u >> 7, c8 = u & 127;
          ull q = __hip_atomic_load((const ull*)(hp + (size_t)row * 1024) + c8,
                                    __ATOMIC_RELAXED, __HIP_MEMORY_SCOPE_AGENT);
          hlds[(row * 128 + c8) ^ ((row & 7) << 1)] = q;
        }
        __syncthreads();
#pragma unroll 4
        for (int kt = 0; kt < 16; ++kt) {
#pragma unroll
          for (int mt = 0; mt < 4; ++mt) {
            const int row = mt * 16 + lr;
            const int uidx = (row * 128 + kt * 8 + lh * 2) ^ ((row & 7) << 1);
            const bf16x8 afr = *(const bf16x8*)((const char*)hlds + (size_t)uidx * 8);
            acc[mt] = __builtin_amdgcn_mfma_f32_16x16x32_bf16(afr, wfrag[kt], acc[mt], 0, 0, 0);
          }
        }
      } else {
#pragma unroll 4
        for (int kt = 0; kt < 16; ++kt) {
#pragma unroll
          for (int mt = 0; mt < 4; ++mt) {
            const ull* hq = (const ull*)(hp + (size_t)(mt * 16 + lr) * 1024 + kt * 32 + lh * 8);
            union { ull q[2]; bf16x8 v; } u;
            u.q[0] = __hip_atomic_load(hq, __ATOMIC_RELAXED, __HIP_MEMORY_SCOPE_AGENT);
            u.q[1] = __hip_atomic_load(hq + 1, __ATOMIC_RELAXED, __HIP_MEMORY_SCOPE_AGENT);
            acc[mt] = __builtin_amdgcn_mfma_f32_16x16x32_bf16(u.v, wfrag[kt], acc[mt], 0, 0, 0);
          }
        }
      }
    }
#pragma unroll
    for (int mt = 0; mt < 4; ++mt)
#pragma unroll
      for (int r = 0; r < 4; ++r) {
        bf16 pv; *(unsigned short*)&pv = pf[mt * 4 + r];
        float v = acc[mt][r] + bb + __bfloat162float(pv);
        xch[(wave * 64 + mt * 16 + lh * 4 + r) * 17 + lr] = v;
      }
    __syncthreads();
    {
      ull pk = 0;
#pragma unroll
      for (int i = 0; i < 4; ++i) {
        int col = sq * 4 + i;
        float gi = xch[(0 * 64 + srow) * 17 + col];
        float gf = xch[(1 * 64 + srow) * 17 + col];
        float gg = xch[(2 * 64 + srow) * 17 + col];
        float go = xch[(3 * 64 + srow) * 17 + col];
        float c = cst[srow * 16 + col];
        float cn = sigm(gf) * c + sigm(gi) * tanh_(gg);
        cst[srow * 16 + col] = cn;
        float h = sigm(go) * tanh_(cn);
        bf16 hb = __float2bfloat16(h);
        pk |= (ull)(*(unsigned short*)&hb) << (16 * i);
      }
      ull* hq = (ull*)(hout + ((size_t)t * 64 + srow) * 1024 + dir * 512 + jb * 16 + sq * 4);
      __hip_atomic_store(hq, pk, __ATOMIC_RELAXED, __HIP_MEMORY_SCOPE_AGENT);
    }
    // release: drain own coherent stores, join waves, then publish epoch (no RMW)
    asm volatile("s_waitcnt vmcnt(0)" ::: "memory");
    __syncthreads();
    if (tid == 0)
      __hip_atomic_store(myflg, (unsigned int)(s + 1), __ATOMIC_RELAXED, __HIP_MEMORY_SCOPE_AGENT);
    // prefetch pre for next step (hides under the next barrier spin)
    if (s < 255) {
      const int tn = dir ? t - 1 : t + 1;
      const bf16* pr = pre + (size_t)tn * 64 * 4096 + colg;
#pragma unroll
      for (int mt = 0; mt < 4; ++mt)
#pragma unroll
        for (int r = 0; r < 4; ++r)
          pf[mt * 4 + r] = *(const unsigned short*)(pr + (size_t)(mt * 16 + lh * 4 + r) * 4096);
    }
  }
}

// ---------------- emit projection: emit[16384][64] = h1 @ WoutB + bout, masked ----------------
__global__ __launch_bounds__(256) void emit_k(const bf16* __restrict__ h1, const bf16* __restrict__ wo,
                                              const float* __restrict__ bout, const int* __restrict__ x,
                                              float* __restrict__ emit) {
  const int tid = threadIdx.x, lane = tid & 63, wave = tid >> 6;
  const int lr = lane & 15, lh = lane >> 4;
  const int mb = blockIdx.x * 64 + wave * 16;
  f32x4 acc[4] = {};
  for (int kt = 0; kt < 32; ++kt) {
    bf16x8 a = *(const bf16x8*)(h1 + (size_t)(mb + lr) * 1024 + kt * 32 + lh * 8);
#pragma unroll
    for (int q = 0; q < 4; ++q) {
      bf16x8 b = *(const bf16x8*)(wo + ((size_t)(q * 32 + kt) * 64 + lane) * 8);
      acc[q] = __builtin_amdgcn_mfma_f32_16x16x32_bf16(a, b, acc[q], 0, 0, 0);
    }
  }
#pragma unroll
  for (int q = 0; q < 4; ++q)
#pragma unroll
    for (int r = 0; r < 4; ++r) {
      int row = mb + lh * 4 + r;
      int col = q * 16 + lr;
      int tt = row >> 6, bi = row & 63;
      float m = (x[bi * 256 + tt] > 0) ? 1.f : 0.f;
      emit[(size_t)row * 64 + col] = (acc[q][r] + bout[col]) * m;
    }
}

// ---------------- CRF forward + gold score, one block per batch element ----------------
__global__ __launch_bounds__(256) void crf_k(const float* __restrict__ emit, const float* __restrict__ trans,
                                             const int* __restrict__ x, const int* __restrict__ y0,
                                             float* __restrict__ out) {
  const int b = blockIdx.x, tid = threadIdx.x;
  __shared__ float tr[4096];
  __shared__ float sc[2][64];
  __shared__ float pm[4][64], ps[4][64];
  __shared__ float redw[4];
  for (int i = tid; i < 4096; i += 256) tr[i] = trans[i];
  if (tid < 64) sc[0][tid] = (tid == 2) ? 0.f : NEGV;  // SOS=2
  __syncthreads();
  {
    const int t = tid;
    const int tag = y0[b * 256 + t];
    const int prev = t ? y0[b * 256 + t - 1] : 2;
    const float m = (x[b * 256 + t] > 0) ? 1.f : 0.f;
    float g = emit[((size_t)t * 64 + b) * 64 + tag] + tr[tag * 64 + prev] * m;
    for (int o = 32; o; o >>= 1) g += __shfl_down(g, o, 64);
    if ((tid & 63) == 0) redw[tid >> 6] = g;
  }
  __syncthreads();
  const float gold = redw[0] + redw[1] + redw[2] + redw[3];
  const int j = tid & 63, kq = tid >> 6;
  int cur = 0;
  for (int t = 0; t < 256; ++t) {
    const float* trj = tr + j * 64 + kq * 16;
    const float* scc = sc[cur] + kq * 16;
    float v[16];
    float mx = -3.0e38f;
#pragma unroll
    for (int k = 0; k < 16; ++k) {
      v[k] = scc[k] + trj[k];
      mx = fmaxf(mx, v[k]);
    }
    float sm = 0.f;
#pragma unroll
    for (int k = 0; k < 16; ++k) sm += __expf(v[k] - mx);
    pm[kq][j] = mx;
    ps[kq][j] = sm;
    __syncthreads();
    if (kq == 0) {
      float M = fmaxf(fmaxf(pm[0][j], pm[1][j]), fmaxf(pm[2][j], pm[3][j]));
      float S = ps[0][j] * __expf(pm[0][j] - M) + ps[1][j] * __expf(pm[1][j] - M) +
                ps[2][j] * __expf(pm[2][j] - M) + ps[3][j] * __expf(pm[3][j] - M);
      float nv = M + __logf(S) + emit[((size_t)t * 64 + b) * 64 + j];
      sc[cur ^ 1][j] = (x[b * 256 + t] > 0) ? nv : sc[cur][j];
    }
    __syncthreads();
    cur ^= 1;
  }
  if (tid < 64) {
    float v2 = sc[cur][tid];
    float M = v2;
    for (int o = 32; o; o >>= 1) M = fmaxf(M, __shfl_xor(M, o, 64));
    float s2 = __expf(v2 - M);
    for (int o = 32; o; o >>= 1) s2 += __shfl_xor(s2, o, 64);
    if (tid == 0) out[b] = M + __logf(s2) - gold;
  }
}

// ---------------- launch ----------------
extern "C" void kernel_launch(void* const* d_in, const int* in_sizes, int n_in, void* d_out, int out_size,
                              void* d_ws, size_t ws_size, hipStream_t stream) {
  (void)in_sizes; (void)n_in; (void)out_size; (void)ws_size;
  const int* x = (const int*)d_in[0];
  const int* y0 = (const int*)d_in[1];
  const float* embed = (const float*)d_in[2];
  const float* Wih0f = (const float*)d_in[3];
  const float* Whh0f = (const float*)d_in[4];
  const float* b0f = (const float*)d_in[5];
  const float* Wih0b = (const float*)d_in[6];
  const float* Whh0b = (const float*)d_in[7];
  const float* b0b = (const float*)d_in[8];
  const float* Wih1f = (const float*)d_in[9];
  const float* Whh1f = (const float*)d_in[10];
  const float* b1f = (const float*)d_in[11];
  const float* Wih1b = (const float*)d_in[12];
  const float* Whh1b = (const float*)d_in[13];
  const float* b1b = (const float*)d_in[14];
  const float* Wout = (const float*)d_in[15];
  const float* bout = (const float*)d_in[16];
  const float* trans = (const float*)d_in[17];

  char* p = (char*)d_ws;
  auto take = [&](size_t n) { char* r = p; p += (n + 255) & ~(size_t)255; return r; };
  unsigned int* flags = (unsigned int*)take(128 * sizeof(unsigned int));  // [layer][dir][32 slots]
  bf16* xs = (bf16*)take(16384ull * 320 * 2);
  bf16* pre = (bf16*)take(16384ull * 4096 * 2);
  bf16* h0 = (bf16*)take(16384ull * 1024 * 2);
  bf16* h1 = (bf16*)take(16384ull * 1024 * 2);
  float* emitb = (float*)take(16384ull * 64 * 4);
  bf16* W0B = (bf16*)take(4096ull * 320 * 2);
  bf16* W1B = (bf16*)take(4096ull * 1024 * 2);
  bf16* WhhB = (bf16*)take(4ull * 1048576 * 2);
  bf16* WoB = (bf16*)take(64ull * 1024 * 2);
  float* bias0 = (float*)take(4096 * 4);
  float* bias1 = (float*)take(4096 * 4);

  hipMemsetAsync(flags, 0, 128 * sizeof(unsigned int), stream);
  hipLaunchKernelGGL(pack_w0, dim3(5120), dim3(256), 0, stream, Wih0f, Wih0b, W0B);
  hipLaunchKernelGGL(pack_whh, dim3(4096), dim3(256), 0, stream, Whh0f, WhhB + 0ull * 1048576);
  hipLaunchKernelGGL(pack_whh, dim3(4096), dim3(256), 0, stream, Whh0b, WhhB + 1ull * 1048576);
  hipLaunchKernelGGL(pack_whh, dim3(4096), dim3(256), 0, stream, Whh1f, WhhB + 2ull * 1048576);
  hipLaunchKernelGGL(pack_whh, dim3(4096), dim3(256), 0, stream, Whh1b, WhhB + 3ull * 1048576);
  hipLaunchKernelGGL(pack_w1, dim3(16384), dim3(256), 0, stream, Wih1f, Wih1b, W1B);
  hipLaunchKernelGGL(pack_wout, dim3(256), dim3(256), 0, stream, Wout, WoB);
  hipLaunchKernelGGL(pack_bias, dim3(16), dim3(256), 0, stream, b0f, b0b, bias0);
  hipLaunchKernelGGL(pack_bias, dim3(16), dim3(256), 0, stream, b1f, b1b, bias1);
  hipLaunchKernelGGL(embed_k, dim3(20480), dim3(256), 0, stream, x, embed, xs);

  hipLaunchKernelGGL(gemm_nt, dim3(256, 16), dim3(256), 0, stream, xs, W0B, pre, 320, 10);
  {
    const bf16* a0 = pre; const bf16* a1 = WhhB; const float* a2 = bias0; bf16* a3 = h0;
    unsigned int* a4 = flags;  // layer0 slots
    void* args[] = {&a0, &a1, &a2, &a3, &a4};
    hipLaunchCooperativeKernel((void*)(&lstm_layer<1>), dim3(32, 2), dim3(256), args, 0, stream);
  }
  hipLaunchKernelGGL(gemm_nt, dim3(256, 16), dim3(256), 0, stream, h0, W1B, pre, 1024, 32);
  {
    const bf16* a0 = pre; const bf16* a1 = WhhB + 2ull * 1048576; const float* a2 = bias1; bf16* a3 = h1;
    unsigned int* a4 = flags + 64;  // layer1 slots
    void* args[] = {&a0, &a1, &a2, &a3, &a4};
    hipLaunchCooperativeKernel((void*)(&lstm_layer<0>), dim3(32, 2), dim3(256), args, 0, stream);
  }
  hipLaunchKernelGGL(emit_k, dim3(256), dim3(256), 0, stream, h1, WoB, bout, x, emitb);
  hipLaunchKernelGGL(crf_k, dim3(64), dim3(256), 0, stream, emitb, trans, x, y0, (float*)d_out);
}

// Round 5
// 3824.643 us; speedup vs baseline: 3.5004x; 2.3276x over previous
//
#include <hip/hip_runtime.h>
#include <hip/hip_bf16.h>

typedef short bf16x8 __attribute__((ext_vector_type(8)));
typedef float f32x4 __attribute__((ext_vector_type(4)));
typedef __hip_bfloat16 bf16;
typedef unsigned long long ull;

#define NEGV -10000.0f

// Problem dims: B=64, T=256, E=300, H=500, K=64(tags), V=32000
// Padded: Ep=320, Hp=512, layer-1 input 2*Hp=1024, gate width 4096 = 2dir*4gate*512

__device__ __forceinline__ float sigm(float v) { return 1.0f / (1.0f + __expf(-v)); }
__device__ __forceinline__ float tanh_(float v) { float e = __expf(2.0f * v); return 1.0f - 2.0f / (e + 1.0f); }

// async global->LDS, 16B per lane, wave-uniform LDS base + lane*16
__device__ __forceinline__ void async_load16(const bf16* g, const char* l) {
  __builtin_amdgcn_global_load_lds((const __attribute__((address_space(1))) void*)g,
                                   (__attribute__((address_space(3))) void*)l, 16, 0, 0);
}

// ---------------- weight packing into MFMA fragment-linear layout ----------------
// B-frag layout: dst[((nt*Kt + kt)*64 + lane)*8 + u] = B[kt*32 + (lane>>4)*8 + u][nt*16 + (lane&15)]

__global__ __launch_bounds__(256) void pack_w0(const float* __restrict__ wf, const float* __restrict__ wb,
                                               bf16* __restrict__ dst) {
  int idx = blockIdx.x * 256 + threadIdx.x;            // 4096*320 = 1310720
  int u = idx & 7, lane = (idx >> 3) & 63, rem = idx >> 9;
  int kt = rem % 10, nt = rem / 10;
  int n = (nt << 4) + (lane & 15), k = (kt << 5) + ((lane >> 4) << 3) + u;
  int d = n >> 11, g = (n >> 9) & 3, j = n & 511;
  float v = 0.f;
  if (j < 500 && k < 300) v = (d ? wb : wf)[(g * 500 + j) * 300 + k];
  dst[idx] = __float2bfloat16(v);
}

__global__ __launch_bounds__(256) void pack_whh(const float* __restrict__ w, bf16* __restrict__ dst) {
  int idx = blockIdx.x * 256 + threadIdx.x;            // 2048*512 = 1048576
  int u = idx & 7, lane = (idx >> 3) & 63, rem = idx >> 9;
  int kt = rem & 15, nt = rem >> 4;
  int n = (nt << 4) + (lane & 15), k = (kt << 5) + ((lane >> 4) << 3) + u;
  int g = n >> 9, j = n & 511;
  float v = 0.f;
  if (j < 500 && k < 500) v = w[(g * 500 + j) * 500 + k];
  dst[idx] = __float2bfloat16(v);
}

__global__ __launch_bounds__(256) void pack_w1(const float* __restrict__ wf, const float* __restrict__ wb,
                                               bf16* __restrict__ dst) {
  int idx = blockIdx.x * 256 + threadIdx.x;            // 4096*1024 = 4194304
  int u = idx & 7, lane = (idx >> 3) & 63, rem = idx >> 9;
  int kt = rem & 31, nt = rem >> 5;
  int n = (nt << 4) + (lane & 15), k = (kt << 5) + ((lane >> 4) << 3) + u;
  int d = n >> 11, g = (n >> 9) & 3, j = n & 511;
  int kk = k & 511;
  int ks = (k < 512) ? kk : 500 + kk;
  float v = 0.f;
  if (j < 500 && kk < 500) v = (d ? wb : wf)[(g * 500 + j) * 1000 + ks];
  dst[idx] = __float2bfloat16(v);
}

__global__ __launch_bounds__(256) void pack_wout(const float* __restrict__ w, bf16* __restrict__ dst) {
  int idx = blockIdx.x * 256 + threadIdx.x;            // 4*32*512 = 65536
  int u = idx & 7, lane = (idx >> 3) & 63, rem = idx >> 9;
  int kt = rem & 31, nt = rem >> 5;
  int n = (nt << 4) + (lane & 15), k = (kt << 5) + ((lane >> 4) << 3) + u;
  int kk = k & 511;
  int ks = (k < 512) ? kk : 500 + kk;
  float v = 0.f;
  if (kk < 500) v = w[n * 1000 + ks];
  dst[idx] = __float2bfloat16(v);
}

__global__ __launch_bounds__(256) void pack_bias(const float* __restrict__ bf_, const float* __restrict__ bb_,
                                                 float* __restrict__ dst) {
  int idx = blockIdx.x * 256 + threadIdx.x;            // 4096
  int d = idx >> 11, g = (idx >> 9) & 3, j = idx & 511;
  dst[idx] = (j < 500) ? (d ? bb_ : bf_)[g * 500 + j] : 0.f;
}

// ---------------- embedding gather -> bf16 [T*B][320] ----------------
__global__ __launch_bounds__(256) void embed_k(const int* __restrict__ x, const float* __restrict__ em,
                                               bf16* __restrict__ xs) {
  int idx = blockIdx.x * 256 + threadIdx.x;            // 16384*320
  int e = idx % 320;
  int row = idx / 320;
  int t = row >> 6, b = row & 63;
  float v = 0.f;
  if (e < 300) {
    int xv = x[b * 256 + t];
    v = em[(size_t)xv * 300 + e];
  }
  xs[idx] = __float2bfloat16(v);
}

// ---------------- generic MFMA GEMM: C[16384][4096] = A[16384][Kdim] @ Bfrag ----------------
__global__ __launch_bounds__(256) void gemm_nt(const bf16* __restrict__ A, const bf16* __restrict__ Bf,
                                               bf16* __restrict__ C, int Kdim, int Kt) {
  const int lane = threadIdx.x & 63, wave = threadIdx.x >> 6;
  const int lr = lane & 15, lh = lane >> 4;
  const int mb = blockIdx.x * 64;
  const int ntb = blockIdx.y * 16 + wave * 4;
  f32x4 acc[4][4] = {};
  for (int kt = 0; kt < Kt; ++kt) {
    bf16x8 a[4], b[4];
#pragma unroll
    for (int mt = 0; mt < 4; ++mt)
      a[mt] = *(const bf16x8*)(A + (size_t)(mb + mt * 16 + lr) * Kdim + kt * 32 + lh * 8);
#pragma unroll
    for (int q = 0; q < 4; ++q)
      b[q] = *(const bf16x8*)(Bf + ((size_t)(ntb + q) * Kt + kt) * 512 + lane * 8);
#pragma unroll
    for (int mt = 0; mt < 4; ++mt)
#pragma unroll
      for (int q = 0; q < 4; ++q)
        acc[mt][q] = __builtin_amdgcn_mfma_f32_16x16x32_bf16(a[mt], b[q], acc[mt][q], 0, 0, 0);
  }
#pragma unroll
  for (int mt = 0; mt < 4; ++mt)
#pragma unroll
    for (int q = 0; q < 4; ++q)
#pragma unroll
      for (int r = 0; r < 4; ++r) {
        int row = mb + mt * 16 + lh * 4 + r;
        int col = (ntb + q) * 16 + lr;
        C[(size_t)row * 4096 + col] = __float2bfloat16(acc[mt][q][r]);
      }
}

// ---------------- cooperative bidirectional LSTM layer ----------------
// grid(32 jb-tiles, 2 dirs), 256 threads (wave = gate). Slot-flag barrier; h tile
// (64x512 bf16 = 64KB) staged per step via async global_load_lds (all 16 loads/wave
// outstanding, one vmcnt drain) with XOR-swizzled global source + matching swizzled
// ds_read (linear LDS dest requirement of global_load_lds).
// SPREAD=1: flags spread 64B apart, only wave 0 polls (lanes 0-31 cover slots).
// SPREAD=0: flags packed, all waves poll (R4 style). A/B for poll contention.
template <int SPREAD>
__global__ __launch_bounds__(256) void lstm_layer(const bf16* __restrict__ pre, const bf16* __restrict__ whh,
                                                  const float* __restrict__ bias, bf16* __restrict__ hout,
                                                  unsigned int* __restrict__ flags) {
  const int tid = threadIdx.x, lane = tid & 63, wave = tid >> 6;
  const int lr = lane & 15, lh = lane >> 4;
  const int jb = blockIdx.x, dir = blockIdx.y;
  unsigned int* flg = flags + dir * 512;                       // this direction's slots
  unsigned int* myflg = flg + (SPREAD ? jb * 16 : jb);
  __shared__ __align__(16) char hlds[65536];  // h tile, swizzled
  __shared__ float xch[4 * 64 * 17];          // [gate][batch][16 cols], stride-17 pad
  __shared__ float cst[64 * 16];              // c-state fp32, persistent across steps
  for (int i = tid; i < 1024; i += 256) cst[i] = 0.f;
  const int colg = dir * 2048 + wave * 512 + jb * 16 + lr;
  const float bb = bias[colg];
  const bf16* wbase = whh + ((size_t)(dir * 128 + wave * 32 + jb) * 16) * 512 + lane * 8;

  // preload recurrent weights into registers (16 frags = 64 VGPRs)
  bf16x8 wfrag[16];
#pragma unroll
  for (int kt = 0; kt < 16; ++kt) wfrag[kt] = *(const bf16x8*)(wbase + kt * 512);

  // prefetch pre for first step
  unsigned short pf[16];
  {
    const bf16* pr = pre + (size_t)(dir ? 255 : 0) * 64 * 4096 + colg;
#pragma unroll
    for (int mt = 0; mt < 4; ++mt)
#pragma unroll
      for (int r = 0; r < 4; ++r)
        pf[mt * 4 + r] = *(const unsigned short*)(pr + (size_t)(mt * 16 + lh * 4 + r) * 4096);
  }

  const int srow = tid >> 2, sq = tid & 3;  // h-store mapping: one 4-col quad per thread

  for (int s = 0; s < 256; ++s) {
    const int t = dir ? 255 - s : s;
    f32x4 acc[4] = {};
    if (s > 0) {
      // wait: all 32 producer blocks of this direction finished step s-1
      if (!SPREAD || wave == 0) {
        for (;;) {
          unsigned int v = __hip_atomic_load(flg + (lane & 31) * (SPREAD ? 16 : 1),
                                             __ATOMIC_RELAXED, __HIP_MEMORY_SCOPE_AGENT);
          if (__all((int)(v >= (unsigned int)s))) break;
        }
      }
      __syncthreads();
      const int tp = dir ? t + 1 : t - 1;
      const bf16* hp = hout + (size_t)tp * 64 * 1024 + dir * 512;
      // async stage: wave w covers rows i*4+w; per row, lane's 16B chunk is taken from
      // the XOR-swizzled source column so LDS (linear dest) ends up swizzle-stored.
#pragma unroll
      for (int i = 0; i < 16; ++i) {
        const int row = i * 4 + wave;
        const int m = (row & 7) << 4;
        const bf16* g = hp + (size_t)row * 1024 + (((lane * 16) ^ m) >> 1);
        async_load16(g, hlds + row * 1024);
      }
      asm volatile("s_waitcnt vmcnt(0)" ::: "memory");
      __syncthreads();
#pragma unroll 4
      for (int kt = 0; kt < 16; ++kt) {
#pragma unroll
        for (int mt = 0; mt < 4; ++mt) {
          const int row = mt * 16 + lr;
          const int cb = (kt * 64 + lh * 16) ^ ((row & 7) << 4);
          const bf16x8 afr = *(const bf16x8*)(hlds + row * 1024 + cb);
          acc[mt] = __builtin_amdgcn_mfma_f32_16x16x32_bf16(afr, wfrag[kt], acc[mt], 0, 0, 0);
        }
      }
    }
#pragma unroll
    for (int mt = 0; mt < 4; ++mt)
#pragma unroll
      for (int r = 0; r < 4; ++r) {
        bf16 pv; *(unsigned short*)&pv = pf[mt * 4 + r];
        float v = acc[mt][r] + bb + __bfloat162float(pv);
        xch[(wave * 64 + mt * 16 + lh * 4 + r) * 17 + lr] = v;
      }
    __syncthreads();
    {
      ull pk = 0;
#pragma unroll
      for (int i = 0; i < 4; ++i) {
        int col = sq * 4 + i;
        float gi = xch[(0 * 64 + srow) * 17 + col];
        float gf = xch[(1 * 64 + srow) * 17 + col];
        float gg = xch[(2 * 64 + srow) * 17 + col];
        float go = xch[(3 * 64 + srow) * 17 + col];
        float c = cst[srow * 16 + col];
        float cn = sigm(gf) * c + sigm(gi) * tanh_(gg);
        cst[srow * 16 + col] = cn;
        float h = sigm(go) * tanh_(cn);
        bf16 hb = __float2bfloat16(h);
        pk |= (ull)(*(unsigned short*)&hb) << (16 * i);
      }
      ull* hq = (ull*)(hout + ((size_t)t * 64 + srow) * 1024 + dir * 512 + jb * 16 + sq * 4);
      __hip_atomic_store(hq, pk, __ATOMIC_RELAXED, __HIP_MEMORY_SCOPE_AGENT);
    }
    // release: drain own coherent stores, join waves, then publish epoch (no RMW)
    asm volatile("s_waitcnt vmcnt(0)" ::: "memory");
    __syncthreads();
    if (tid == 0)
      __hip_atomic_store(myflg, (unsigned int)(s + 1), __ATOMIC_RELAXED, __HIP_MEMORY_SCOPE_AGENT);
    // prefetch pre for next step (hides under the next barrier spin)
    if (s < 255) {
      const int tn = dir ? t - 1 : t + 1;
      const bf16* pr = pre + (size_t)tn * 64 * 4096 + colg;
#pragma unroll
      for (int mt = 0; mt < 4; ++mt)
#pragma unroll
        for (int r = 0; r < 4; ++r)
          pf[mt * 4 + r] = *(const unsigned short*)(pr + (size_t)(mt * 16 + lh * 4 + r) * 4096);
    }
  }
}

// ---------------- emit projection: emit[16384][64] = h1 @ WoutB + bout, masked ----------------
__global__ __launch_bounds__(256) void emit_k(const bf16* __restrict__ h1, const bf16* __restrict__ wo,
                                              const float* __restrict__ bout, const int* __restrict__ x,
                                              float* __restrict__ emit) {
  const int tid = threadIdx.x, lane = tid & 63, wave = tid >> 6;
  const int lr = lane & 15, lh = lane >> 4;
  const int mb = blockIdx.x * 64 + wave * 16;
  f32x4 acc[4] = {};
  for (int kt = 0; kt < 32; ++kt) {
    bf16x8 a = *(const bf16x8*)(h1 + (size_t)(mb + lr) * 1024 + kt * 32 + lh * 8);
#pragma unroll
    for (int q = 0; q < 4; ++q) {
      bf16x8 b = *(const bf16x8*)(wo + ((size_t)(q * 32 + kt) * 64 + lane) * 8);
      acc[q] = __builtin_amdgcn_mfma_f32_16x16x32_bf16(a, b, acc[q], 0, 0, 0);
    }
  }
#pragma unroll
  for (int q = 0; q < 4; ++q)
#pragma unroll
    for (int r = 0; r < 4; ++r) {
      int row = mb + lh * 4 + r;
      int col = q * 16 + lr;
      int tt = row >> 6, bi = row & 63;
      float m = (x[bi * 256 + tt] > 0) ? 1.f : 0.f;
      emit[(size_t)row * 64 + col] = (acc[q][r] + bout[col]) * m;
    }
}

// ---------------- CRF forward + gold score, one block per batch element ----------------
__global__ __launch_bounds__(256) void crf_k(const float* __restrict__ emit, const float* __restrict__ trans,
                                             const int* __restrict__ x, const int* __restrict__ y0,
                                             float* __restrict__ out) {
  const int b = blockIdx.x, tid = threadIdx.x;
  __shared__ float tr[4096];
  __shared__ float sc[2][64];
  __shared__ float pm[4][64], ps[4][64];
  __shared__ float redw[4];
  for (int i = tid; i < 4096; i += 256) tr[i] = trans[i];
  if (tid < 64) sc[0][tid] = (tid == 2) ? 0.f : NEGV;  // SOS=2
  __syncthreads();
  {
    const int t = tid;
    const int tag = y0[b * 256 + t];
    const int prev = t ? y0[b * 256 + t - 1] : 2;
    const float m = (x[b * 256 + t] > 0) ? 1.f : 0.f;
    float g = emit[((size_t)t * 64 + b) * 64 + tag] + tr[tag * 64 + prev] * m;
    for (int o = 32; o; o >>= 1) g += __shfl_down(g, o, 64);
    if ((tid & 63) == 0) redw[tid >> 6] = g;
  }
  __syncthreads();
  const float gold = redw[0] + redw[1] + redw[2] + redw[3];
  const int j = tid & 63, kq = tid >> 6;
  int cur = 0;
  for (int t = 0; t < 256; ++t) {
    const float* trj = tr + j * 64 + kq * 16;
    const float* scc = sc[cur] + kq * 16;
    float v[16];
    float mx = -3.0e38f;
#pragma unroll
    for (int k = 0; k < 16; ++k) {
      v[k] = scc[k] + trj[k];
      mx = fmaxf(mx, v[k]);
    }
    float sm = 0.f;
#pragma unroll
    for (int k = 0; k < 16; ++k) sm += __expf(v[k] - mx);
    pm[kq][j] = mx;
    ps[kq][j] = sm;
    __syncthreads();
    if (kq == 0) {
      float M = fmaxf(fmaxf(pm[0][j], pm[1][j]), fmaxf(pm[2][j], pm[3][j]));
      float S = ps[0][j] * __expf(pm[0][j] - M) + ps[1][j] * __expf(pm[1][j] - M) +
                ps[2][j] * __expf(pm[2][j] - M) + ps[3][j] * __expf(pm[3][j] - M);
      float nv = M + __logf(S) + emit[((size_t)t * 64 + b) * 64 + j];
      sc[cur ^ 1][j] = (x[b * 256 + t] > 0) ? nv : sc[cur][j];
    }
    __syncthreads();
    cur ^= 1;
  }
  if (tid < 64) {
    float v2 = sc[cur][tid];
    float M = v2;
    for (int o = 32; o; o >>= 1) M = fmaxf(M, __shfl_xor(M, o, 64));
    float s2 = __expf(v2 - M);
    for (int o = 32; o; o >>= 1) s2 += __shfl_xor(s2, o, 64);
    if (tid == 0) out[b] = M + __logf(s2) - gold;
  }
}

// ---------------- launch ----------------
extern "C" void kernel_launch(void* const* d_in, const int* in_sizes, int n_in, void* d_out, int out_size,
                              void* d_ws, size_t ws_size, hipStream_t stream) {
  (void)in_sizes; (void)n_in; (void)out_size; (void)ws_size;
  const int* x = (const int*)d_in[0];
  const int* y0 = (const int*)d_in[1];
  const float* embed = (const float*)d_in[2];
  const float* Wih0f = (const float*)d_in[3];
  const float* Whh0f = (const float*)d_in[4];
  const float* b0f = (const float*)d_in[5];
  const float* Wih0b = (const float*)d_in[6];
  const float* Whh0b = (const float*)d_in[7];
  const float* b0b = (const float*)d_in[8];
  const float* Wih1f = (const float*)d_in[9];
  const float* Whh1f = (const float*)d_in[10];
  const float* b1f = (const float*)d_in[11];
  const float* Wih1b = (const float*)d_in[12];
  const float* Whh1b = (const float*)d_in[13];
  const float* b1b = (const float*)d_in[14];
  const float* Wout = (const float*)d_in[15];
  const float* bout = (const float*)d_in[16];
  const float* trans = (const float*)d_in[17];

  char* p = (char*)d_ws;
  auto take = [&](size_t n) { char* r = p; p += (n + 255) & ~(size_t)255; return r; };
  unsigned int* flags = (unsigned int*)take(2048 * sizeof(unsigned int));  // [layer][dir][slots]
  bf16* xs = (bf16*)take(16384ull * 320 * 2);
  bf16* pre = (bf16*)take(16384ull * 4096 * 2);
  bf16* h0 = (bf16*)take(16384ull * 1024 * 2);
  bf16* h1 = (bf16*)take(16384ull * 1024 * 2);
  float* emitb = (float*)take(16384ull * 64 * 4);
  bf16* W0B = (bf16*)take(4096ull * 320 * 2);
  bf16* W1B = (bf16*)take(4096ull * 1024 * 2);
  bf16* WhhB = (bf16*)take(4ull * 1048576 * 2);
  bf16* WoB = (bf16*)take(64ull * 1024 * 2);
  float* bias0 = (float*)take(4096 * 4);
  float* bias1 = (float*)take(4096 * 4);

  hipMemsetAsync(flags, 0, 2048 * sizeof(unsigned int), stream);
  hipLaunchKernelGGL(pack_w0, dim3(5120), dim3(256), 0, stream, Wih0f, Wih0b, W0B);
  hipLaunchKernelGGL(pack_whh, dim3(4096), dim3(256), 0, stream, Whh0f, WhhB + 0ull * 1048576);
  hipLaunchKernelGGL(pack_whh, dim3(4096), dim3(256), 0, stream, Whh0b, WhhB + 1ull * 1048576);
  hipLaunchKernelGGL(pack_whh, dim3(4096), dim3(256), 0, stream, Whh1f, WhhB + 2ull * 1048576);
  hipLaunchKernelGGL(pack_whh, dim3(4096), dim3(256), 0, stream, Whh1b, WhhB + 3ull * 1048576);
  hipLaunchKernelGGL(pack_w1, dim3(16384), dim3(256), 0, stream, Wih1f, Wih1b, W1B);
  hipLaunchKernelGGL(pack_wout, dim3(256), dim3(256), 0, stream, Wout, WoB);
  hipLaunchKernelGGL(pack_bias, dim3(16), dim3(256), 0, stream, b0f, b0b, bias0);
  hipLaunchKernelGGL(pack_bias, dim3(16), dim3(256), 0, stream, b1f, b1b, bias1);
  hipLaunchKernelGGL(embed_k, dim3(20480), dim3(256), 0, stream, x, embed, xs);

  hipLaunchKernelGGL(gemm_nt, dim3(256, 16), dim3(256), 0, stream, xs, W0B, pre, 320, 10);
  {
    const bf16* a0 = pre; const bf16* a1 = WhhB; const float* a2 = bias0; bf16* a3 = h0;
    unsigned int* a4 = flags;  // layer0: spread flags, single-wave poll
    void* args[] = {&a0, &a1, &a2, &a3, &a4};
    hipLaunchCooperativeKernel((void*)(&lstm_layer<1>), dim3(32, 2), dim3(256), args, 0, stream);
  }
  hipLaunchKernelGGL(gemm_nt, dim3(256, 16), dim3(256), 0, stream, h0, W1B, pre, 1024, 32);
  {
    const bf16* a0 = pre; const bf16* a1 = WhhB + 2ull * 1048576; const float* a2 = bias1; bf16* a3 = h1;
    unsigned int* a4 = flags + 1024;  // layer1: packed flags, all-wave poll
    void* args[] = {&a0, &a1, &a2, &a3, &a4};
    hipLaunchCooperativeKernel((void*)(&lstm_layer<0>), dim3(32, 2), dim3(256), args, 0, stream);
  }
  hipLaunchKernelGGL(emit_k, dim3(256), dim3(256), 0, stream, h1, WoB, bout, x, emitb);
  hipLaunchKernelGGL(crf_k, dim3(64), dim3(256), 0, stream, emitb, trans, x, y0, (float*)d_out);
}